// Round 1
// baseline (514.262 us; speedup 1.0000x reference)
//
#include <hip/hip_runtime.h>
#include <math.h>

#define B_   64
#define N_   1024
#define FIN_ 256
#define FO_  64

// ---------------------------------------------------------------------------
// Kernel 1: h = input @ W   (M = B*N = 65536 rows, K=256, N=64)
//           e2[r] = h[r,:] . a2          (fused epilogue)
// Tile: 128 rows x 64 cols, 256 threads, MI=8 x MF=4 per thread.
// in_lds padded to 65 floats/row: a-frag b32 reads land on distinct banks
// (rows {mi,8+mi,16+mi,24+mi} -> banks mi+{0,8,16,24}).
// ---------------------------------------------------------------------------
__global__ __launch_bounds__(256, 2) void k1_hproj(
    const float* __restrict__ input,   // [M][256]
    const float* __restrict__ W,       // [256][64]
    const float* __restrict__ a,       // [128]
    float* __restrict__ h,             // [M][64]   (workspace)
    float* __restrict__ e2)            // [M]       (workspace)
{
    __shared__ float in_lds[128][65];
    __shared__ float W_lds[64][64];
    const int t  = threadIdx.x;
    const int tx = t & 15;     // f-group: f = tx*4 .. +3
    const int ty = t >> 4;     // 0..15
    const int r0 = blockIdx.x * 128;

    float acc[8][4] = {};

    for (int k0 = 0; k0 < FIN_; k0 += 64) {
        // stage input[r0 .. r0+127][k0 .. k0+63], transpose-free, padded rows
        #pragma unroll
        for (int it = 0; it < 8; ++it) {
            const int row = ty + it * 16;
            const int kq  = tx * 4;
            const float4 v = *reinterpret_cast<const float4*>(
                &input[(size_t)(r0 + row) * FIN_ + k0 + kq]);
            in_lds[row][kq + 0] = v.x;
            in_lds[row][kq + 1] = v.y;
            in_lds[row][kq + 2] = v.z;
            in_lds[row][kq + 3] = v.w;
        }
        // stage W[k0 .. k0+63][0..63]
        #pragma unroll
        for (int it = 0; it < 4; ++it) {
            const int kk = ty + it * 16;
            *reinterpret_cast<float4*>(&W_lds[kk][tx * 4]) =
                *reinterpret_cast<const float4*>(&W[(size_t)(k0 + kk) * FO_ + tx * 4]);
        }
        __syncthreads();

        #pragma unroll 4
        for (int k = 0; k < 64; ++k) {
            float af[8];
            #pragma unroll
            for (int mi = 0; mi < 8; ++mi) af[mi] = in_lds[ty * 8 + mi][k];
            const float4 bf = *reinterpret_cast<const float4*>(&W_lds[k][tx * 4]);
            #pragma unroll
            for (int mi = 0; mi < 8; ++mi) {
                acc[mi][0] = fmaf(af[mi], bf.x, acc[mi][0]);
                acc[mi][1] = fmaf(af[mi], bf.y, acc[mi][1]);
                acc[mi][2] = fmaf(af[mi], bf.z, acc[mi][2]);
                acc[mi][3] = fmaf(af[mi], bf.w, acc[mi][3]);
            }
        }
        __syncthreads();
    }

    // epilogue: write h, reduce e2 = h . a2 across the 16 tx lanes (lane bits 0..3)
    const float4 a2v = *reinterpret_cast<const float4*>(&a[FO_ + tx * 4]);
    #pragma unroll
    for (int mi = 0; mi < 8; ++mi) {
        const int row = r0 + ty * 8 + mi;
        float4 hv;
        hv.x = acc[mi][0]; hv.y = acc[mi][1]; hv.z = acc[mi][2]; hv.w = acc[mi][3];
        *reinterpret_cast<float4*>(&h[(size_t)row * FO_ + tx * 4]) = hv;

        float p = acc[mi][0] * a2v.x + acc[mi][1] * a2v.y +
                  acc[mi][2] * a2v.z + acc[mi][3] * a2v.w;
        p += __shfl_xor(p, 1);
        p += __shfl_xor(p, 2);
        p += __shfl_xor(p, 4);
        p += __shfl_xor(p, 8);
        if (tx == 0) e2[row] = p;
    }
}

// ---------------------------------------------------------------------------
// Kernel 2: fused masked softmax attention + PV + ELU.
//   e[b,i,j] = relu(S1*h[b,i,j>>4] + e2[b,j]);  w = adj ? exp(e) : 0
//   out[b,i,f] = elu( (sum_j w*h[b,j,f]) / (sum_j w) )
// No max-subtraction needed: unmasked e >= 0 and bounded (~40), so exp() and
// the f32 sums stay far from overflow; masked weights are exactly 0, matching
// the reference's exp(-9e15 - m) == 0 underflow. Ratios are identical.
// One workgroup = (batch b, 128 i-rows), loops 32-wide j-tiles.
// ---------------------------------------------------------------------------
__global__ __launch_bounds__(256, 2) void k2_attn(
    const float* __restrict__ h,
    const int*   __restrict__ adj,
    const float* __restrict__ a,
    const float* __restrict__ e2,
    float* __restrict__ out)
{
    __shared__ float h_lds[32][64];     // h tile [j][f]
    __shared__ float wT[32][128];       // weights transposed [j][i]
    __shared__ float c2[128][2];        // S1*h[b][i0+i][g0], g0+1
    __shared__ float e2_lds[32];
    __shared__ float den_lds[128][2];

    const int t  = threadIdx.x;
    const int tx = t & 15;              // f-group
    const int ty = t >> 4;              // 0..15 -> rows ty*8..+7
    const int b  = blockIdx.y;
    const int i0 = blockIdx.x * 128;

    // S1 = sum(a1) (tiny, L2-cached, computed redundantly per thread)
    float S1 = 0.f;
    #pragma unroll
    for (int f = 0; f < FO_; f += 4) {
        const float4 av = *reinterpret_cast<const float4*>(&a[f]);
        S1 += av.x + av.y + av.z + av.w;
    }

    float acc[8][4] = {};
    float denreg = 0.f;

    const int wi  = t >> 1;            // weight-phase row 0..127
    const int ws  = t & 1;             // slot (which 16-j half)
    const int jl0 = ws * 16;

    const float* hb     = h + (size_t)b * N_ * FO_;
    const int*   adjrow = adj + ((size_t)b * N_ + i0 + wi) * N_;

    for (int jt = 0; jt < N_; jt += 32) {
        // ---- stage phase ----
        #pragma unroll
        for (int it = 0; it < 2; ++it) {
            const int idx = it * 256 + t;          // 0..511 float4s, coalesced
            const int j   = idx >> 4;
            const int fq  = (idx & 15) * 4;
            *reinterpret_cast<float4*>(&h_lds[j][fq]) =
                *reinterpret_cast<const float4*>(&hb[(size_t)(jt + j) * FO_ + fq]);
        }
        if (t < 32) e2_lds[t] = e2[(size_t)b * N_ + jt + t];
        if (t < 128) {
            // g = (jt+jl)>>4 takes only 2 values within a 32-wide tile
            const float2 hv = *reinterpret_cast<const float2*>(
                &hb[(size_t)(i0 + t) * FO_ + (jt >> 4)]);
            c2[t][0] = S1 * hv.x;
            c2[t][1] = S1 * hv.y;
        }
        __syncthreads();

        // ---- weight phase: 16 weights/thread, adj via int4 (coalesced) ----
        const float c0 = c2[wi][0];
        const float c1 = c2[wi][1];
        #pragma unroll
        for (int d = 0; d < 16; d += 4) {
            const int4 av = *reinterpret_cast<const int4*>(&adjrow[jt + jl0 + d]);
            const int aa[4] = { av.x, av.y, av.z, av.w };
            #pragma unroll
            for (int dd = 0; dd < 4; ++dd) {
                const int jl = jl0 + d + dd;
                const float cg = (jl & 16) ? c1 : c0;
                const float ev = fmaxf(cg + e2_lds[jl], 0.f);
                const float w  = aa[dd] ? __expf(ev) : 0.f;
                denreg += w;
                wT[jl][wi] = w;
            }
        }
        __syncthreads();

        // ---- GEMM phase: acc[i][f] += w[i][j] * h[j][f] ----
        #pragma unroll 4
        for (int jl = 0; jl < 32; ++jl) {
            const float4 w0 = *reinterpret_cast<const float4*>(&wT[jl][ty * 8]);
            const float4 w1 = *reinterpret_cast<const float4*>(&wT[jl][ty * 8 + 4]);
            const float4 hv = *reinterpret_cast<const float4*>(&h_lds[jl][tx * 4]);
            acc[0][0] = fmaf(w0.x, hv.x, acc[0][0]); acc[0][1] = fmaf(w0.x, hv.y, acc[0][1]);
            acc[0][2] = fmaf(w0.x, hv.z, acc[0][2]); acc[0][3] = fmaf(w0.x, hv.w, acc[0][3]);
            acc[1][0] = fmaf(w0.y, hv.x, acc[1][0]); acc[1][1] = fmaf(w0.y, hv.y, acc[1][1]);
            acc[1][2] = fmaf(w0.y, hv.z, acc[1][2]); acc[1][3] = fmaf(w0.y, hv.w, acc[1][3]);
            acc[2][0] = fmaf(w0.z, hv.x, acc[2][0]); acc[2][1] = fmaf(w0.z, hv.y, acc[2][1]);
            acc[2][2] = fmaf(w0.z, hv.z, acc[2][2]); acc[2][3] = fmaf(w0.z, hv.w, acc[2][3]);
            acc[3][0] = fmaf(w0.w, hv.x, acc[3][0]); acc[3][1] = fmaf(w0.w, hv.y, acc[3][1]);
            acc[3][2] = fmaf(w0.w, hv.z, acc[3][2]); acc[3][3] = fmaf(w0.w, hv.w, acc[3][3]);
            acc[4][0] = fmaf(w1.x, hv.x, acc[4][0]); acc[4][1] = fmaf(w1.x, hv.y, acc[4][1]);
            acc[4][2] = fmaf(w1.x, hv.z, acc[4][2]); acc[4][3] = fmaf(w1.x, hv.w, acc[4][3]);
            acc[5][0] = fmaf(w1.y, hv.x, acc[5][0]); acc[5][1] = fmaf(w1.y, hv.y, acc[5][1]);
            acc[5][2] = fmaf(w1.y, hv.z, acc[5][2]); acc[5][3] = fmaf(w1.y, hv.w, acc[5][3]);
            acc[6][0] = fmaf(w1.z, hv.x, acc[6][0]); acc[6][1] = fmaf(w1.z, hv.y, acc[6][1]);
            acc[6][2] = fmaf(w1.z, hv.z, acc[6][2]); acc[6][3] = fmaf(w1.z, hv.w, acc[6][3]);
            acc[7][0] = fmaf(w1.w, hv.x, acc[7][0]); acc[7][1] = fmaf(w1.w, hv.y, acc[7][1]);
            acc[7][2] = fmaf(w1.w, hv.z, acc[7][2]); acc[7][3] = fmaf(w1.w, hv.w, acc[7][3]);
        }
        __syncthreads();
    }

    den_lds[wi][ws] = denreg;
    __syncthreads();

    // ---- normalize + ELU + store ----
    #pragma unroll
    for (int mi = 0; mi < 8; ++mi) {
        const int i = ty * 8 + mi;
        const float den = den_lds[i][0] + den_lds[i][1];
        const float inv = 1.0f / den;
        float v[4];
        #pragma unroll
        for (int q = 0; q < 4; ++q) {
            const float x = acc[mi][q] * inv;
            v[q] = (x > 0.f) ? x : expm1f(x);
        }
        float4 o; o.x = v[0]; o.y = v[1]; o.z = v[2]; o.w = v[3];
        *reinterpret_cast<float4*>(
            &out[((size_t)b * N_ + i0 + i) * FO_ + tx * 4]) = o;
    }
}

extern "C" void kernel_launch(void* const* d_in, const int* in_sizes, int n_in,
                              void* d_out, int out_size, void* d_ws, size_t ws_size,
                              hipStream_t stream) {
    const float* input = (const float*)d_in[0];   // [64][1024][256] f32
    const int*   adj   = (const int*)d_in[1];     // [64][1024][1024] i32
    const float* W     = (const float*)d_in[2];   // [256][64] f32
    const float* a     = (const float*)d_in[3];   // [128] f32
    float* out = (float*)d_out;                   // [64][1024][64] f32

    float* h  = (float*)d_ws;                             // 16 MiB
    float* e2 = (float*)((char*)d_ws + (size_t)B_ * N_ * FO_ * sizeof(float));

    k1_hproj<<<dim3((B_ * N_) / 128), dim3(256), 0, stream>>>(input, W, a, h, e2);
    k2_attn<<<dim3(N_ / 128, B_), dim3(256), 0, stream>>>(h, adj, a, e2, out);
}